// Round 4
// baseline (466.490 us; speedup 1.0000x reference)
//
#include <hip/hip_runtime.h>
#include <math.h>

// Problem dims (fixed by the reference)
#define B_DIM 8
#define L_DIM 2048
#define H_DIM 1024
#define N2_DIM 32

typedef __attribute__((ext_vector_type(8))) short short8;
typedef __attribute__((ext_vector_type(4))) float floatx4;

__device__ __forceinline__ unsigned short f2bf(float f) {   // RNE float->bf16 (finite inputs)
    unsigned u = __float_as_uint(f);
    return (unsigned short)((u + 0x7fffu + ((u >> 16) & 1u)) >> 16);
}
__device__ __forceinline__ float bf2f(unsigned short s) {
    return __uint_as_float((unsigned)s << 16);
}

// async global->LDS, 16B per lane; LDS dest = wave-uniform base + lane*16
#define GLOADLDS16(G, S) __builtin_amdgcn_global_load_lds( \
    (const __attribute__((address_space(1))) unsigned int*)(G), \
    (__attribute__((address_space(3))) unsigned int*)(S), 16, 0, 0)

// ---------------------------------------------------------------------------
// Kernel 1: per-(h,n) S4 parameters
// params[h*32+n] = { wr, wi, 2*Ck_re, 2*Ck_im },  w = exp(dt*A), Ck = C*(exp(dt*A)-1)/A
// (same op order as the reference's fp32 path -> same rounding behavior)
// ---------------------------------------------------------------------------
__global__ __launch_bounds__(256) void s4_param_kernel(
    const float* __restrict__ log_dt,
    const float* __restrict__ C_re, const float* __restrict__ C_im,
    const float* __restrict__ log_A_re, const float* __restrict__ A_im,
    float4* __restrict__ params)
{
    int idx = blockIdx.x * 256 + threadIdx.x;       // 0 .. H*N2-1
    int h = idx >> 5;
    float dt  = expf(log_dt[h]);
    float Are = -expf(log_A_re[idx]);
    float Aim = A_im[idx];
    float dr = Are * dt;
    float di = Aim * dt;
    float ex = expf(dr);
    float wr = ex * cosf(di);
    float wi = ex * sinf(di);
    float nr = wr - 1.0f, ni = wi;
    float inv = 1.0f / (Are * Are + Aim * Aim);
    float qr = (nr * Are + ni * Aim) * inv;
    float qi = (ni * Are - nr * Aim) * inv;
    float cr = C_re[idx], ci = C_im[idx];
    float ckr = cr * qr - ci * qi;
    float cki = cr * qi + ci * qr;
    params[idx] = make_float4(wr, wi, 2.0f * ckr, 2.0f * cki);
}

// ---------------------------------------------------------------------------
// Kernel 1b: split W (fp32 [2048][1024]) -> bf16 hi/lo buffers (same layout)
// ---------------------------------------------------------------------------
__global__ __launch_bounds__(256) void wsplit_kernel(
    const float* __restrict__ W,
    unsigned short* __restrict__ Whi, unsigned short* __restrict__ Wlo)
{
    int i4 = (blockIdx.x * 256 + threadIdx.x) * 4;
    float4 w = *(const float4*)&W[i4];
    float wf[4] = {w.x, w.y, w.z, w.w};
    unsigned short h[4], l[4];
    #pragma unroll
    for (int j = 0; j < 4; ++j) {
        h[j] = f2bf(wf[j]);
        l[j] = f2bf(wf[j] - bf2f(h[j]));
    }
    uint2 hp, lp;
    hp.x = (unsigned)h[0] | ((unsigned)h[1] << 16);
    hp.y = (unsigned)h[2] | ((unsigned)h[3] << 16);
    lp.x = (unsigned)l[0] | ((unsigned)l[1] << 16);
    lp.y = (unsigned)l[2] | ((unsigned)l[3] << 16);
    *(uint2*)&Whi[i4] = hp;
    *(uint2*)&Wlo[i4] = lp;
}

// ---------------------------------------------------------------------------
// DPP butterfly add (row-local, VALU pipe)
// ---------------------------------------------------------------------------
template <int CTRL>
__device__ __forceinline__ float dppadd(float v)
{
    int s = __builtin_amdgcn_update_dpp(0, __float_as_int(v), CTRL, 0xF, 0xF, false);
    return v + __int_as_float(s);
}

// ---------------------------------------------------------------------------
// Kernel 2: S4 scan + D*x + exact GELU -> bf16 hi/lo, tiled-transposed layout
//   G{hi,lo}[h>>4][p = b*L+l][h&15]   (16 bf16 = 32B contiguous per (p,htile))
// 16 lanes per (b,h) group; lane owns complex states n=lane, n=lane+16.
// y[l] = 2*Re(sum_n Ck_n * s_n[l]),  s_n[l] = w_n*s_n[l-1] + x[l]
// (exact linear-conv equivalent of the reference's zero-padded FFT path)
// ---------------------------------------------------------------------------
__global__ __launch_bounds__(256) void s4_scan_kernel(
    const float* __restrict__ x,          // [B, L, H]
    const float4* __restrict__ params,    // [H*32]
    const float* __restrict__ D,          // [H]
    unsigned short* __restrict__ Ghi,     // [64][16384][16]
    unsigned short* __restrict__ Glo)
{
    __shared__ float xs[2][32][16];       // [buf][l within round][h within block]
    __shared__ unsigned int ts[32][17];   // [l][h] packed (hi<<16)|lo, pad 17
    const int tid  = threadIdx.x;
    const int grp  = tid >> 4;            // 0..15 : h within block
    const int lane = tid & 15;            // 0..15 : state lane within group
    const int gid0 = blockIdx.x * 16;
    const int gid  = gid0 + grp;
    const int b    = gid0 >> 10;          // uniform over block
    const int h    = gid & 1023;
    const int h0   = gid0 & 1023;         // multiple of 16
    const int htile = h0 >> 4;
    const size_t xbase = ((size_t)b * L_DIM) * H_DIM + (size_t)h0;

    const float4 p0 = params[(h << 5) + lane];
    const float4 p1 = params[(h << 5) + 16 + lane];
    const float  Dh = D[h];

    // out-phase mapping: thread -> (l2, pair-of-h)
    const int l2 = tid >> 3;              // 0..31
    const int h2 = tid & 7;               // 0..7

    {
        int i0 = tid, i1 = tid + 256;
        xs[0][i0 >> 4][i0 & 15] = x[xbase + (size_t)(i0 >> 4) * H_DIM + (i0 & 15)];
        xs[0][i1 >> 4][i1 & 15] = x[xbase + (size_t)(i1 >> 4) * H_DIM + (i1 & 15)];
    }
    __syncthreads();

    float sr0 = 0.f, si0 = 0.f, sr1 = 0.f, si1 = 0.f;

    for (int r = 0; r < 64; ++r) {
        const int buf = r & 1;
        // T14: issue next round's global loads early, write to LDS late
        float xa0 = 0.f, xa1 = 0.f;
        if (r + 1 < 64) {
            int l1 = (r + 1) * 32;
            int i0 = tid, i1 = tid + 256;
            xa0 = x[xbase + (size_t)(l1 + (i0 >> 4)) * H_DIM + (i0 & 15)];
            xa1 = x[xbase + (size_t)(l1 + (i1 >> 4)) * H_DIM + (i1 & 15)];
        }
        float y0 = 0.f, y1 = 0.f;
        #pragma unroll
        for (int j = 0; j < 32; ++j) {
            float xv = xs[buf][j][grp];   // broadcast within group
            float t0  = fmaf(-p0.y, si0, xv);
            float nr0 = fmaf(p0.x, sr0, t0);
            si0 = fmaf(p0.x, si0, p0.y * sr0);
            sr0 = nr0;
            float t1  = fmaf(-p1.y, si1, xv);
            float nr1 = fmaf(p1.x, sr1, t1);
            si1 = fmaf(p1.x, si1, p1.y * sr1);
            sr1 = nr1;
            float c = fmaf(p0.z, sr0, -p0.w * si0) + fmaf(p1.z, sr1, -p1.w * si1);
            c = dppadd<0xB1>(c);    // xor 1
            c = dppadd<0x4E>(c);    // xor 2
            c = dppadd<0x141>(c);   // row_half_mirror (sum of 8)
            c = dppadd<0x140>(c);   // row_mirror (sum of 16)
            if (j < 16) { if (lane == j)        y0 = c; }
            else        { if (lane == (j - 16)) y1 = c; }
        }
        // per-thread: y for l = r*32+lane and +16
        float xva = xs[buf][lane][grp];
        float xvb = xs[buf][lane + 16][grp];
        float ya = fmaf(Dh, xva, y0);
        float yb = fmaf(Dh, xvb, y1);
        float ga = 0.5f * ya * (1.0f + erff(ya * 0.70710678118654752f));
        float gb = 0.5f * yb * (1.0f + erff(yb * 0.70710678118654752f));
        {
            unsigned short ha = f2bf(ga), la = f2bf(ga - bf2f(ha));
            unsigned short hb = f2bf(gb), lb = f2bf(gb - bf2f(hb));
            ts[lane][grp]      = ((unsigned)ha << 16) | la;
            ts[lane + 16][grp] = ((unsigned)hb << 16) | lb;
        }
        if (r + 1 < 64) {   // late LDS write of next round's x
            int i0 = tid, i1 = tid + 256;
            xs[buf ^ 1][i0 >> 4][i0 & 15] = xa0;
            xs[buf ^ 1][i1 >> 4][i1 & 15] = xa1;
        }
        __syncthreads();    // ts ready + next x staged
        // out-phase: 2 h per thread, 32B-contiguous runs per l-row
        {
            unsigned v0 = ts[l2][h2 * 2];
            unsigned v1 = ts[l2][h2 * 2 + 1];
            unsigned hiw = (v1 & 0xffff0000u) | (v0 >> 16);
            unsigned low = (v1 << 16) | (v0 & 0xffffu);
            size_t p   = (size_t)b * L_DIM + r * 32 + l2;
            size_t off = ((size_t)htile * 16384 + p) * 16 + h2 * 2;
            *(unsigned*)&Ghi[off] = hiw;
            *(unsigned*)&Glo[off] = low;
        }
        __syncthreads();    // ts consumed before next round overwrites
    }
}

// ---------------------------------------------------------------------------
// Kernel 3: split-bf16 MFMA GEMM (z = W@g + b) + GLU + residual
// z error ~4e-6 rel: Wh*gh + Wh*gl + Wl*gh (lo*lo dropped).
// Block: 128 W-rows (rows 0-63 = "a" half o=hbase+m; 64-127 = "g" half
// o=1024+hbase+m) x 128 p-cols, BK=32. 4 waves: wm=w>>1 (half), wn=w&1
// (p-half); wave-tile 64x64 = 4x4 frags of 16x16, 48 MFMA/K-step.
//
// LDS tiles [row][k] bf16, 64B rows, slot-swizzled:
//   content(row, slot s) = logical kb (s ^ ((row>>1)&3))
// write side: global_load_lds lane L -> row L>>2, slot L&3 (linear dest);
//   per-lane GLOBAL src pre-swizzled: kb = (L&3) ^ ((L>>3)&3)
// read side: lane ln: row = .. + (ln&15), slot = (ln>>4) ^ (((ln&15)>>1)&3)
// -> exact 2-way max bank aliasing (free, m136); both sides consistent.
// ---------------------------------------------------------------------------
__global__ __launch_bounds__(256, 2) void s4_gemm_glu_kernel(
    const unsigned short* __restrict__ Whi, const unsigned short* __restrict__ Wlo,
    const unsigned short* __restrict__ Ghi, const unsigned short* __restrict__ Glo,
    const float* __restrict__ bias,  // [2H]
    const float* __restrict__ x,     // [p][1024]
    float* __restrict__ out)         // [p][1024]
{
    // staging: 2 bufs x {Ahi,Alo,Bhi,Blo} x 8KB = 64KB ; epilogue overlay:
    // zbufA/zbufG: [128 p][68 f32] = 34816B each -> 69632B total
    __shared__ __align__(16) char smem[69632];
    const int tid = threadIdx.x;
    const int ln  = tid & 63;
    const int w   = tid >> 6;

    // XCD-aware bijective swizzle (2048 blocks, 8 XCDs, round-robin dispatch):
    // XCD x runs i = 0..255 in order; (i&1) toggles mt so same-nt pairs are
    // ADJACENT in time on one XCD -> second block's B-panel (512KB) is L2-hot.
    // Each XCD touches only 2 mt -> 1MB of W panels, L2-resident throughout.
    const int xcd = blockIdx.x & 7;
    const int i   = blockIdx.x >> 3;       // 0..255
    const int mt  = xcd * 2 + (i & 1);     // 0..15
    const int nt  = i >> 1;                // 0..127
    const int hbase = mt * 64;
    const int p0 = nt * 128;

    // ---- staging setup (wave w stages tile w: 0=Ahi 1=Alo 2=Bhi 3=Blo) ----
    const int rr  = ln >> 2;                       // row within 16-row issue
    const int kbl = (ln & 3) ^ ((ln >> 3) & 3);    // logical kb for this lane
    const bool isA = (w < 2);
    const unsigned short* sbase = isA ? ((w == 1) ? Wlo : Whi)
                                      : ((w == 3) ? Glo : Ghi);
    const unsigned short* lanePtr;
    if (isA) {  // row hbase+rr (half offsets added per sub), k = kbl*8
        lanePtr = sbase + (((size_t)(hbase + rr)) << 10) + kbl * 8;
    } else {    // plane kbl>>1, row p0+rr, within-plane half (kbl&1)*8
        lanePtr = sbase + ((size_t)(kbl >> 1) * 16384 + (size_t)(p0 + rr)) * 16
                        + (kbl & 1) * 8;
    }
    char* ldsW = smem + w * 8192;

    // ---- fragment-read lane constants ----
    const int m_lane = ln & 15;
    const int kq = ln >> 4;
    const int slotOff = ((kq ^ ((m_lane >> 1) & 3)) << 4);  // bytes
    const int wm = w >> 1, wn = w & 1;

    floatx4 acc[4][4];
    #pragma unroll
    for (int fi = 0; fi < 4; ++fi)
        #pragma unroll
        for (int fj = 0; fj < 4; ++fj) acc[fi][fj] = (floatx4){0.f, 0.f, 0.f, 0.f};

    // prologue: stage K-step 0 into buf 0
    #pragma unroll
    for (int s = 0; s < 8; ++s) {
        size_t so = isA ? ((s < 4) ? (size_t)s * 16384
                                   : (size_t)(s - 4) * 16384 + (size_t)1048576)
                        : (size_t)s * 256;
        GLOADLDS16(lanePtr + so, ldsW + s * 1024);
    }
    __syncthreads();

    const size_t kAdv = isA ? (size_t)32 : (size_t)524288;  // elems per K-step

    for (int t = 0; t < 32; ++t) {
        const int buf = t & 1;
        if (t + 1 < 32) {   // stage next K-step into other buffer
            const unsigned short* src = lanePtr + (size_t)(t + 1) * kAdv;
            char* dst = ldsW + (buf ^ 1) * 32768;
            #pragma unroll
            for (int s = 0; s < 8; ++s) {
                size_t so = isA ? ((s < 4) ? (size_t)s * 16384
                                           : (size_t)(s - 4) * 16384 + (size_t)1048576)
                                : (size_t)s * 256;
                GLOADLDS16(src + so, dst + s * 1024);
            }
        }
        const char* base = smem + buf * 32768;
        short8 ah[4], al[4], bh[4], bl[4];
        #pragma unroll
        for (int f = 0; f < 4; ++f) {
            int offA = (wm * 64 + f * 16 + m_lane) * 64 + slotOff;
            ah[f] = *(const short8*)(base + offA);
            al[f] = *(const short8*)(base + 8192 + offA);
            int offB = (wn * 64 + f * 16 + m_lane) * 64 + slotOff;
            bh[f] = *(const short8*)(base + 16384 + offB);
            bl[f] = *(const short8*)(base + 24576 + offB);
        }
        #pragma unroll
        for (int fi = 0; fi < 4; ++fi)
            #pragma unroll
            for (int fj = 0; fj < 4; ++fj) {
                acc[fi][fj] = __builtin_amdgcn_mfma_f32_16x16x32_bf16(ah[fi], bh[fj], acc[fi][fj], 0, 0, 0);
                acc[fi][fj] = __builtin_amdgcn_mfma_f32_16x16x32_bf16(ah[fi], bl[fj], acc[fi][fj], 0, 0, 0);
                acc[fi][fj] = __builtin_amdgcn_mfma_f32_16x16x32_bf16(al[fi], bh[fj], acc[fi][fj], 0, 0, 0);
            }
        __syncthreads();   // staging complete (vmcnt0) + reads done before reuse
    }

    // ---- epilogue: accs -> zbufs [p][68] (transposed, padded) ----
    float* zb = (float*)(smem + wm * 34816);
    #pragma unroll
    for (int fi = 0; fi < 4; ++fi)
        #pragma unroll
        for (int fj = 0; fj < 4; ++fj) {
            int prow = wn * 64 + fj * 16 + m_lane;
            *(floatx4*)&zb[prow * 68 + fi * 16 + kq * 4] = acc[fi][fj];
        }
    __syncthreads();

    const float* zA = (const float*)smem;
    const float* zG = (const float*)(smem + 34816);
    const int pq = tid >> 3;          // 0..31
    const int hs = tid & 7;           // 0..7
    const int hcol = hbase + hs * 8;  // 8 contiguous h per thread
    float4 ba0 = *(const float4*)&bias[hcol];
    float4 ba1 = *(const float4*)&bias[hcol + 4];
    float4 bg0 = *(const float4*)&bias[H_DIM + hcol];
    float4 bg1 = *(const float4*)&bias[H_DIM + hcol + 4];
    float baf[8] = {ba0.x, ba0.y, ba0.z, ba0.w, ba1.x, ba1.y, ba1.z, ba1.w};
    float bgf[8] = {bg0.x, bg0.y, bg0.z, bg0.w, bg1.x, bg1.y, bg1.z, bg1.w};

    #pragma unroll
    for (int ip = 0; ip < 4; ++ip) {
        int ploc = ip * 32 + pq;
        size_t obase = (((size_t)(p0 + ploc)) << 10) + hcol;
        const float* za = &zA[ploc * 68 + hs * 8];
        const float* zg = &zG[ploc * 68 + hs * 8];
        float4 za0 = *(const float4*)za,       za1 = *(const float4*)(za + 4);
        float4 zg0 = *(const float4*)zg,       zg1 = *(const float4*)(zg + 4);
        float4 x0  = *(const float4*)&x[obase], x1 = *(const float4*)&x[obase + 4];
        float zaf[8] = {za0.x, za0.y, za0.z, za0.w, za1.x, za1.y, za1.z, za1.w};
        float zgf[8] = {zg0.x, zg0.y, zg0.z, zg0.w, zg1.x, zg1.y, zg1.z, zg1.w};
        float xf[8]  = {x0.x, x0.y, x0.z, x0.w, x1.x, x1.y, x1.z, x1.w};
        float of[8];
        #pragma unroll
        for (int j = 0; j < 8; ++j) {
            float zaj = zaf[j] + baf[j];
            float zgj = zgf[j] + bgf[j];
            float sg  = 1.0f / (1.0f + expf(-zgj));
            of[j] = fmaf(zaj, sg, xf[j]);
        }
        *(float4*)&out[obase]     = make_float4(of[0], of[1], of[2], of[3]);
        *(float4*)&out[obase + 4] = make_float4(of[4], of[5], of[6], of[7]);
    }
}

// ---------------------------------------------------------------------------
extern "C" void kernel_launch(void* const* d_in, const int* in_sizes, int n_in,
                              void* d_out, int out_size, void* d_ws, size_t ws_size,
                              hipStream_t stream)
{
    const float* x        = (const float*)d_in[0];
    const float* log_dt   = (const float*)d_in[1];
    const float* C_re     = (const float*)d_in[2];
    const float* C_im     = (const float*)d_in[3];
    const float* log_A_re = (const float*)d_in[4];
    const float* A_im     = (const float*)d_in[5];
    const float* D        = (const float*)d_in[6];
    const float* W        = (const float*)d_in[7];
    const float* bias     = (const float*)d_in[8];
    float* out = (float*)d_out;

    // workspace layout (bytes):
    // params 512K | Whi 4M | Wlo 4M | Ghi 32M | Glo 32M   (total ~72.5 MB)
    char* ws = (char*)d_ws;
    float4*         params = (float4*)ws;
    unsigned short* Whi    = (unsigned short*)(ws + 524288);
    unsigned short* Wlo    = (unsigned short*)(ws + 524288 + 4194304);
    unsigned short* Ghi    = (unsigned short*)(ws + 524288 + 2 * 4194304);
    unsigned short* Glo    = (unsigned short*)(ws + 524288 + 2 * 4194304 + 33554432);

    s4_param_kernel<<<(H_DIM * N2_DIM) / 256, 256, 0, stream>>>(
        log_dt, C_re, C_im, log_A_re, A_im, params);

    wsplit_kernel<<<(2 * H_DIM * H_DIM) / 1024, 256, 0, stream>>>(W, Whi, Wlo);

    s4_scan_kernel<<<(B_DIM * H_DIM) / 16, 256, 0, stream>>>(x, params, D, Ghi, Glo);

    // 16 m-tiles x 128 n-tiles = 2048 blocks
    s4_gemm_glu_kernel<<<2048, 256, 0, stream>>>(Whi, Wlo, Ghi, Glo, bias, x, out);
}

// Round 9
// 462.255 us; speedup vs baseline: 1.0092x; 1.0092x over previous
//
#include <hip/hip_runtime.h>
#include <math.h>

// Problem dims (fixed by the reference)
#define B_DIM 8
#define L_DIM 2048
#define H_DIM 1024
#define N2_DIM 32

typedef __attribute__((ext_vector_type(8))) short short8;
typedef __attribute__((ext_vector_type(4))) float floatx4;

__device__ __forceinline__ unsigned short f2bf(float f) {   // RNE float->bf16 (finite inputs)
    unsigned u = __float_as_uint(f);
    return (unsigned short)((u + 0x7fffu + ((u >> 16) & 1u)) >> 16);
}
__device__ __forceinline__ float bf2f(unsigned short s) {
    return __uint_as_float((unsigned)s << 16);
}

// async global->LDS, 16B per lane; LDS dest = wave-uniform base + lane*16
#define GLOADLDS16(G, S) __builtin_amdgcn_global_load_lds( \
    (const __attribute__((address_space(1))) unsigned int*)(G), \
    (__attribute__((address_space(3))) unsigned int*)(S), 16, 0, 0)

// ---------------------------------------------------------------------------
// Kernel 1: per-(h,n) S4 parameters
// params[h*32+n] = { wr, wi, 2*Ck_re, 2*Ck_im },  w = exp(dt*A), Ck = C*(exp(dt*A)-1)/A
// ---------------------------------------------------------------------------
__global__ __launch_bounds__(256) void s4_param_kernel(
    const float* __restrict__ log_dt,
    const float* __restrict__ C_re, const float* __restrict__ C_im,
    const float* __restrict__ log_A_re, const float* __restrict__ A_im,
    float4* __restrict__ params)
{
    int idx = blockIdx.x * 256 + threadIdx.x;       // 0 .. H*N2-1
    int h = idx >> 5;
    float dt  = expf(log_dt[h]);
    float Are = -expf(log_A_re[idx]);
    float Aim = A_im[idx];
    float dr = Are * dt;
    float di = Aim * dt;
    float ex = expf(dr);
    float wr = ex * cosf(di);
    float wi = ex * sinf(di);
    float nr = wr - 1.0f, ni = wi;
    float inv = 1.0f / (Are * Are + Aim * Aim);
    float qr = (nr * Are + ni * Aim) * inv;
    float qi = (ni * Are - nr * Aim) * inv;
    float cr = C_re[idx], ci = C_im[idx];
    float ckr = cr * qr - ci * qi;
    float cki = cr * qi + ci * qr;
    params[idx] = make_float4(wr, wi, 2.0f * ckr, 2.0f * cki);
}

// ---------------------------------------------------------------------------
// Kernel 1b: split W (fp32 [2048][1024]) -> bf16 hi/lo buffers (same layout)
// ---------------------------------------------------------------------------
__global__ __launch_bounds__(256) void wsplit_kernel(
    const float* __restrict__ W,
    unsigned short* __restrict__ Whi, unsigned short* __restrict__ Wlo)
{
    int i4 = (blockIdx.x * 256 + threadIdx.x) * 4;
    float4 w = *(const float4*)&W[i4];
    float wf[4] = {w.x, w.y, w.z, w.w};
    unsigned short h[4], l[4];
    #pragma unroll
    for (int j = 0; j < 4; ++j) {
        h[j] = f2bf(wf[j]);
        l[j] = f2bf(wf[j] - bf2f(h[j]));
    }
    uint2 hp, lp;
    hp.x = (unsigned)h[0] | ((unsigned)h[1] << 16);
    hp.y = (unsigned)h[2] | ((unsigned)h[3] << 16);
    lp.x = (unsigned)l[0] | ((unsigned)l[1] << 16);
    lp.y = (unsigned)l[2] | ((unsigned)l[3] << 16);
    *(uint2*)&Whi[i4] = hp;
    *(uint2*)&Wlo[i4] = lp;
}

// ---------------------------------------------------------------------------
// DPP butterfly add (row-local, VALU pipe)
// ---------------------------------------------------------------------------
template <int CTRL>
__device__ __forceinline__ float dppadd(float v)
{
    int s = __builtin_amdgcn_update_dpp(0, __float_as_int(v), CTRL, 0xF, 0xF, false);
    return v + __int_as_float(s);
}

// ---------------------------------------------------------------------------
// Kernel 2: S4 scan + D*x + exact GELU -> bf16 hi/lo, tiled-transposed layout
//   G{hi,lo}[h>>4][p = b*L+l][h&15]   (16 bf16 = 32B contiguous per (p,htile))
// 16 lanes per (b,h) group; lane owns complex states n=lane, n=lane+16.
// y[l] = 2*Re(sum_n Ck_n * s_n[l]),  s_n[l] = w_n*s_n[l-1] + x[l]
// (exact linear-conv equivalent of the reference's zero-padded FFT path)
// ---------------------------------------------------------------------------
__global__ __launch_bounds__(256) void s4_scan_kernel(
    const float* __restrict__ x,          // [B, L, H]
    const float4* __restrict__ params,    // [H*32]
    const float* __restrict__ D,          // [H]
    unsigned short* __restrict__ Ghi,     // [64][16384][16]
    unsigned short* __restrict__ Glo)
{
    __shared__ float xs[2][32][16];       // [buf][l within round][h within block]
    __shared__ unsigned int ts[32][17];   // [l][h] packed (hi<<16)|lo, pad 17
    const int tid  = threadIdx.x;
    const int grp  = tid >> 4;            // 0..15 : h within block
    const int lane = tid & 15;            // 0..15 : state lane within group
    const int gid0 = blockIdx.x * 16;
    const int gid  = gid0 + grp;
    const int b    = gid0 >> 10;          // uniform over block
    const int h    = gid & 1023;
    const int h0   = gid0 & 1023;         // multiple of 16
    const int htile = h0 >> 4;
    const size_t xbase = ((size_t)b * L_DIM) * H_DIM + (size_t)h0;

    const float4 p0 = params[(h << 5) + lane];
    const float4 p1 = params[(h << 5) + 16 + lane];
    const float  Dh = D[h];

    // out-phase mapping: thread -> (l2, pair-of-h)
    const int l2 = tid >> 3;              // 0..31
    const int h2 = tid & 7;               // 0..7

    {
        int i0 = tid, i1 = tid + 256;
        xs[0][i0 >> 4][i0 & 15] = x[xbase + (size_t)(i0 >> 4) * H_DIM + (i0 & 15)];
        xs[0][i1 >> 4][i1 & 15] = x[xbase + (size_t)(i1 >> 4) * H_DIM + (i1 & 15)];
    }
    __syncthreads();

    float sr0 = 0.f, si0 = 0.f, sr1 = 0.f, si1 = 0.f;

    for (int r = 0; r < 64; ++r) {
        const int buf = r & 1;
        // T14: issue next round's global loads early, write to LDS late
        float xa0 = 0.f, xa1 = 0.f;
        if (r + 1 < 64) {
            int l1 = (r + 1) * 32;
            int i0 = tid, i1 = tid + 256;
            xa0 = x[xbase + (size_t)(l1 + (i0 >> 4)) * H_DIM + (i0 & 15)];
            xa1 = x[xbase + (size_t)(l1 + (i1 >> 4)) * H_DIM + (i1 & 15)];
        }
        float y0 = 0.f, y1 = 0.f;
        #pragma unroll
        for (int j = 0; j < 32; ++j) {
            float xv = xs[buf][j][grp];   // broadcast within group
            float t0  = fmaf(-p0.y, si0, xv);
            float nr0 = fmaf(p0.x, sr0, t0);
            si0 = fmaf(p0.x, si0, p0.y * sr0);
            sr0 = nr0;
            float t1  = fmaf(-p1.y, si1, xv);
            float nr1 = fmaf(p1.x, sr1, t1);
            si1 = fmaf(p1.x, si1, p1.y * sr1);
            sr1 = nr1;
            float c = fmaf(p0.z, sr0, -p0.w * si0) + fmaf(p1.z, sr1, -p1.w * si1);
            c = dppadd<0xB1>(c);    // xor 1
            c = dppadd<0x4E>(c);    // xor 2
            c = dppadd<0x141>(c);   // row_half_mirror (sum of 8)
            c = dppadd<0x140>(c);   // row_mirror (sum of 16)
            if (j < 16) { if (lane == j)        y0 = c; }
            else        { if (lane == (j - 16)) y1 = c; }
        }
        // per-thread: y for l = r*32+lane and +16
        float xva = xs[buf][lane][grp];
        float xvb = xs[buf][lane + 16][grp];
        float ya = fmaf(Dh, xva, y0);
        float yb = fmaf(Dh, xvb, y1);
        float ga = 0.5f * ya * (1.0f + erff(ya * 0.70710678118654752f));
        float gb = 0.5f * yb * (1.0f + erff(yb * 0.70710678118654752f));
        {
            unsigned short ha = f2bf(ga), la = f2bf(ga - bf2f(ha));
            unsigned short hb = f2bf(gb), lb = f2bf(gb - bf2f(hb));
            ts[lane][grp]      = ((unsigned)ha << 16) | la;
            ts[lane + 16][grp] = ((unsigned)hb << 16) | lb;
        }
        if (r + 1 < 64) {   // late LDS write of next round's x
            int i0 = tid, i1 = tid + 256;
            xs[buf ^ 1][i0 >> 4][i0 & 15] = xa0;
            xs[buf ^ 1][i1 >> 4][i1 & 15] = xa1;
        }
        __syncthreads();    // ts ready + next x staged
        // out-phase: 2 h per thread, 32B-contiguous runs per l-row
        {
            unsigned v0 = ts[l2][h2 * 2];
            unsigned v1 = ts[l2][h2 * 2 + 1];
            unsigned hiw = (v1 & 0xffff0000u) | (v0 >> 16);
            unsigned low = (v1 << 16) | (v0 & 0xffffu);
            size_t p   = (size_t)b * L_DIM + r * 32 + l2;
            size_t off = ((size_t)htile * 16384 + p) * 16 + h2 * 2;
            *(unsigned*)&Ghi[off] = hiw;
            *(unsigned*)&Glo[off] = low;
        }
        __syncthreads();    // ts consumed before next round overwrites
    }
}

// ---------------------------------------------------------------------------
// Kernel 3: split-bf16 MFMA GEMM (z = W@g + b) + GLU + residual
// z error ~4e-6 rel: Wh*gh + Wh*gl + Wl*gh (lo*lo dropped).
// Block: 128 W-rows (rows 0-63 = "a" half o=hbase+m; 64-127 = "g" half
// o=1024+hbase+m) x 128 p-cols, BK=32. 4 waves: wm=w>>1 (half), wn=w&1
// (p-half); wave-tile 64x64 = 4x4 frags of 16x16, 48 MFMA/K-step.
//
// T4 pipeline (counted vmcnt, never 0 in steady state; raw s_barrier):
//   iter t: ds_read(buf t&1) -> MFMA -> BARRIER_A (all reads done)
//           -> stage(t+2 -> buf t&1) -> vmcnt(8) [= stage(t+1) done; it was
//              issued a full iteration earlier, so the wait is ~free]
//           -> BARRIER_B (stage t+1 visible to all waves)
// vs. __syncthreads() which drained vmcnt to 0 every K-step
// (loads issued only ~230 wave-cycles earlier; HBM latency uncovered).
// Barrier-count is wave-uniform (t uniform) -> no deadlock; only VMEM ops in
// the loop are the 8 global_load_lds per wave -> inline vmcnt counts exact.
//
// LDS tiles [row][k] bf16, 64B rows, slot-swizzled:
//   content(row, slot s) = logical kb (s ^ ((row>>1)&3))
// write side: global_load_lds lane L -> row L>>2, slot L&3 (linear dest);
//   per-lane GLOBAL src pre-swizzled: kb = (L&3) ^ ((L>>3)&3)
// read side: lane ln: row = .. + (ln&15), slot = (ln>>4) ^ (((ln&15)>>1)&3)
// -> exact 2-way max bank aliasing (free, m136); both sides consistent.
// ---------------------------------------------------------------------------
__global__ __launch_bounds__(256, 2) void s4_gemm_glu_kernel(
    const unsigned short* __restrict__ Whi, const unsigned short* __restrict__ Wlo,
    const unsigned short* __restrict__ Ghi, const unsigned short* __restrict__ Glo,
    const float* __restrict__ bias,  // [2H]
    const float* __restrict__ x,     // [p][1024]
    float* __restrict__ out)         // [p][1024]
{
    // staging: 2 bufs x {Ahi,Alo,Bhi,Blo} x 8KB = 64KB ; epilogue overlay:
    // zbufA/zbufG: [128 p][68 f32] = 34816B each -> 69632B total
    __shared__ __align__(16) char smem[69632];
    const int tid = threadIdx.x;
    const int ln  = tid & 63;
    const int w   = tid >> 6;

    // XCD-aware bijective swizzle (2048 blocks, 8 XCDs, round-robin dispatch):
    // XCD x runs i = 0..255 in order; (i&1) toggles mt so same-nt pairs are
    // ADJACENT in time on one XCD -> second block's B-panel (512KB) is L2-hot.
    // Each XCD touches only 2 mt -> 1MB of W panels, L2-resident throughout.
    const int xcd = blockIdx.x & 7;
    const int i   = blockIdx.x >> 3;       // 0..255
    const int mt  = xcd * 2 + (i & 1);     // 0..15
    const int nt  = i >> 1;                // 0..127
    const int hbase = mt * 64;
    const int p0 = nt * 128;

    // ---- staging setup (wave w stages tile w: 0=Ahi 1=Alo 2=Bhi 3=Blo) ----
    const int rr  = ln >> 2;                       // row within 16-row issue
    const int kbl = (ln & 3) ^ ((ln >> 3) & 3);    // logical kb for this lane
    const bool isA = (w < 2);
    const unsigned short* sbase = isA ? ((w == 1) ? Wlo : Whi)
                                      : ((w == 3) ? Glo : Ghi);
    const unsigned short* lanePtr;
    if (isA) {  // row hbase+rr (half offsets added per sub), k = kbl*8
        lanePtr = sbase + (((size_t)(hbase + rr)) << 10) + kbl * 8;
    } else {    // plane kbl>>1, row p0+rr, within-plane half (kbl&1)*8
        lanePtr = sbase + ((size_t)(kbl >> 1) * 16384 + (size_t)(p0 + rr)) * 16
                        + (kbl & 1) * 8;
    }
    char* ldsW = smem + w * 8192;

    // ---- fragment-read lane constants ----
    const int m_lane = ln & 15;
    const int kq = ln >> 4;
    const int slotOff = ((kq ^ ((m_lane >> 1) & 3)) << 4);  // bytes
    const int wm = w >> 1, wn = w & 1;

    floatx4 acc[4][4];
    #pragma unroll
    for (int fi = 0; fi < 4; ++fi)
        #pragma unroll
        for (int fj = 0; fj < 4; ++fj) acc[fi][fj] = (floatx4){0.f, 0.f, 0.f, 0.f};

    const size_t kAdv = isA ? (size_t)32 : (size_t)524288;  // elems per K-step

    // prologue: stage K-step 0 -> buf0, K-step 1 -> buf1 (16 loads in flight)
    #pragma unroll
    for (int s = 0; s < 8; ++s) {
        size_t so = isA ? ((s < 4) ? (size_t)s * 16384
                                   : (size_t)(s - 4) * 16384 + (size_t)1048576)
                        : (size_t)s * 256;
        GLOADLDS16(lanePtr + so, ldsW + s * 1024);
    }
    #pragma unroll
    for (int s = 0; s < 8; ++s) {
        size_t so = isA ? ((s < 4) ? (size_t)s * 16384
                                   : (size_t)(s - 4) * 16384 + (size_t)1048576)
                        : (size_t)s * 256;
        GLOADLDS16(lanePtr + kAdv + so, ldsW + 32768 + s * 1024);
    }
    asm volatile("s_waitcnt vmcnt(8)" ::: "memory");   // stage(0) done
    __builtin_amdgcn_s_barrier();                      // stage(0) visible
    __builtin_amdgcn_sched_barrier(0);

    for (int t = 0; t < 32; ++t) {
        const int buf = t & 1;
        const char* base = smem + buf * 32768;
        short8 ah[4], al[4], bh[4], bl[4];
        #pragma unroll
        for (int f = 0; f < 4; ++f) {
            int offA = (wm * 64 + f * 16 + m_lane) * 64 + slotOff;
            ah[f] = *(const short8*)(base + offA);
            al[f] = *(const short8*)(base + 8192 + offA);
            int offB = (wn * 64 + f * 16 + m_lane) * 64 + slotOff;
            bh[f] = *(const short8*)(base + 16384 + offB);
            bl[f] = *(const short8*)(base + 24576 + offB);
        }
        __builtin_amdgcn_s_setprio(1);
        #pragma unroll
        for (int fi = 0; fi < 4; ++fi)
            #pragma unroll
            for (int fj = 0; fj < 4; ++fj) {
                acc[fi][fj] = __builtin_amdgcn_mfma_f32_16x16x32_bf16(ah[fi], bh[fj], acc[fi][fj], 0, 0, 0);
                acc[fi][fj] = __builtin_amdgcn_mfma_f32_16x16x32_bf16(ah[fi], bl[fj], acc[fi][fj], 0, 0, 0);
                acc[fi][fj] = __builtin_amdgcn_mfma_f32_16x16x32_bf16(al[fi], bh[fj], acc[fi][fj], 0, 0, 0);
            }
        __builtin_amdgcn_s_setprio(0);
        __builtin_amdgcn_sched_barrier(0);
        __builtin_amdgcn_s_barrier();          // A: all waves done reading buf
        __builtin_amdgcn_sched_barrier(0);
        if (t + 2 < 32) {
            // stage K-step t+2 into the buffer just consumed
            const unsigned short* src = lanePtr + (size_t)(t + 2) * kAdv;
            char* dst = smem + buf * 32768 + w * 8192;
            #pragma unroll
            for (int s = 0; s < 8; ++s) {
                size_t so = isA ? ((s < 4) ? (size_t)s * 16384
                                           : (size_t)(s - 4) * 16384 + (size_t)1048576)
                                : (size_t)s * 256;
                GLOADLDS16(src + so, dst + s * 1024);
            }
            asm volatile("s_waitcnt vmcnt(8)" ::: "memory");  // stage(t+1) done
        } else if (t + 2 == 32) {
            asm volatile("s_waitcnt vmcnt(0)" ::: "memory");  // stage(31) done
        }
        if (t < 31) {
            __builtin_amdgcn_s_barrier();      // B: stage(t+1) visible
            __builtin_amdgcn_sched_barrier(0);
        }
    }

    // ---- epilogue: accs -> zbufs [p][68] (transposed, padded) ----
    // (BARRIER_A of t=31 guarantees staging reads are done before overwrite)
    float* zb = (float*)(smem + wm * 34816);
    #pragma unroll
    for (int fi = 0; fi < 4; ++fi)
        #pragma unroll
        for (int fj = 0; fj < 4; ++fj) {
            int prow = wn * 64 + fj * 16 + m_lane;
            *(floatx4*)&zb[prow * 68 + fi * 16 + kq * 4] = acc[fi][fj];
        }
    __syncthreads();

    const float* zA = (const float*)smem;
    const float* zG = (const float*)(smem + 34816);
    const int pq = tid >> 3;          // 0..31
    const int hs = tid & 7;           // 0..7
    const int hcol = hbase + hs * 8;  // 8 contiguous h per thread
    float4 ba0 = *(const float4*)&bias[hcol];
    float4 ba1 = *(const float4*)&bias[hcol + 4];
    float4 bg0 = *(const float4*)&bias[H_DIM + hcol];
    float4 bg1 = *(const float4*)&bias[H_DIM + hcol + 4];
    float baf[8] = {ba0.x, ba0.y, ba0.z, ba0.w, ba1.x, ba1.y, ba1.z, ba1.w};
    float bgf[8] = {bg0.x, bg0.y, bg0.z, bg0.w, bg1.x, bg1.y, bg1.z, bg1.w};

    #pragma unroll
    for (int ip = 0; ip < 4; ++ip) {
        int ploc = ip * 32 + pq;
        size_t obase = (((size_t)(p0 + ploc)) << 10) + hcol;
        const float* za = &zA[ploc * 68 + hs * 8];
        const float* zg = &zG[ploc * 68 + hs * 8];
        float4 za0 = *(const float4*)za,       za1 = *(const float4*)(za + 4);
        float4 zg0 = *(const float4*)zg,       zg1 = *(const float4*)(zg + 4);
        float4 x0  = *(const float4*)&x[obase], x1 = *(const float4*)&x[obase + 4];
        float zaf[8] = {za0.x, za0.y, za0.z, za0.w, za1.x, za1.y, za1.z, za1.w};
        float zgf[8] = {zg0.x, zg0.y, zg0.z, zg0.w, zg1.x, zg1.y, zg1.z, zg1.w};
        float xf[8]  = {x0.x, x0.y, x0.z, x0.w, x1.x, x1.y, x1.z, x1.w};
        float of[8];
        #pragma unroll
        for (int j = 0; j < 8; ++j) {
            float zaj = zaf[j] + baf[j];
            float zgj = zgf[j] + bgf[j];
            float sg  = 1.0f / (1.0f + expf(-zgj));
            of[j] = fmaf(zaj, sg, xf[j]);
        }
        *(float4*)&out[obase]     = make_float4(of[0], of[1], of[2], of[3]);
        *(float4*)&out[obase + 4] = make_float4(of[4], of[5], of[6], of[7]);
    }
}

// ---------------------------------------------------------------------------
extern "C" void kernel_launch(void* const* d_in, const int* in_sizes, int n_in,
                              void* d_out, int out_size, void* d_ws, size_t ws_size,
                              hipStream_t stream)
{
    const float* x        = (const float*)d_in[0];
    const float* log_dt   = (const float*)d_in[1];
    const float* C_re     = (const float*)d_in[2];
    const float* C_im     = (const float*)d_in[3];
    const float* log_A_re = (const float*)d_in[4];
    const float* A_im     = (const float*)d_in[5];
    const float* D        = (const float*)d_in[6];
    const float* W        = (const float*)d_in[7];
    const float* bias     = (const float*)d_in[8];
    float* out = (float*)d_out;

    // workspace layout (bytes):
    // params 512K | Whi 4M | Wlo 4M | Ghi 32M | Glo 32M   (total ~72.5 MB)
    char* ws = (char*)d_ws;
    float4*         params = (float4*)ws;
    unsigned short* Whi    = (unsigned short*)(ws + 524288);
    unsigned short* Wlo    = (unsigned short*)(ws + 524288 + 4194304);
    unsigned short* Ghi    = (unsigned short*)(ws + 524288 + 2 * 4194304);
    unsigned short* Glo    = (unsigned short*)(ws + 524288 + 2 * 4194304 + 33554432);

    s4_param_kernel<<<(H_DIM * N2_DIM) / 256, 256, 0, stream>>>(
        log_dt, C_re, C_im, log_A_re, A_im, params);

    wsplit_kernel<<<(2 * H_DIM * H_DIM) / 1024, 256, 0, stream>>>(W, Whi, Wlo);

    s4_scan_kernel<<<(B_DIM * H_DIM) / 16, 256, 0, stream>>>(x, params, D, Ghi, Glo);

    // 16 m-tiles x 128 n-tiles = 2048 blocks
    s4_gemm_glu_kernel<<<2048, 256, 0, stream>>>(Whi, Wlo, Ghi, Glo, bias, x, out);
}